// Round 4
// baseline (96.874 us; speedup 1.0000x reference)
//
#include <hip/hip_runtime.h>

// EdgeConv2d: B=4, C=128, N=4096, K=16, COUT=128, GROUPS=4
//
// Factorization: grouped 1x1 conv on feat=[x_i, x_j - x_i] is linear in the
// gathered node vectors. Precompute per-node Y[b][n][o]:
//   o in [0,32):    Y = W[o] . x[b, 0:64,  n]   (group 0, consumes x_i only)
//   o in [32,64):   Y = W[o] . x[b, 64:128,n]   (group 1, x_i only)
//   o in [64,96):   Y = W[o] . x[b, 0:64,  n]   (group 2, applied to x_j-x_i)
//   o in [96,128):  Y = W[o] . x[b, 64:128,n]   (group 3, x_j-x_i)
// Then per edge (n,k) with i1=edge_index[1], j=edge_index[0]:
//   o <  64: pre = Y[i1][o]               + bias[o]
//   o >= 64: pre = Y[j][o] - Y[i1][o]     + bias[o]
//   out[b][o][n] = mean_k relu(pre)
// Compute drops from 4.3 GFLOP (per-edge matvec) to 268 MFLOP (per-node),
// and the gather becomes contiguous 512B rows of node-major Y (L2-resident
// per XCD with chunked swizzle).

#define BB   4
#define CC   128
#define NN   4096
#define KK   16
#define CO   128

// ---------------------------------------------------------------------------
// Kernel 1: Y[b][n][o] = sum_c W[o][c] * x[b][cbase(o)+c][n]
// 256 blocks x 512 threads. lane = node (coalesced x), wave = 16 o-channels.
// ---------------------------------------------------------------------------
__global__ __launch_bounds__(512) void precompute_y(
    const float* __restrict__ x,   // [B,128,N]
    const float* __restrict__ w,   // [128,64]
    float* __restrict__ Y)         // [B,N,128] node-major
{
    const int lane = threadIdx.x & 63;
    // force wave id into SGPR so weight loads scalarize (s_load)
    const int wv = __builtin_amdgcn_readfirstlane((int)(threadIdx.x >> 6)); // 0..7

    // chunked XCD swizzle: 256 blocks -> 32 consecutive work items per XCD
    const int bid  = blockIdx.x;
    const int work = (bid & 7) * ((int)gridDim.x >> 3) + (bid >> 3);

    const int gnode = work * 64 + lane;     // global node id = b*N + n
    const int b = gnode >> 12;              // N = 4096
    const int n = gnode & (NN - 1);

    const int obase = wv * 16;
    const int cbase = ((wv >> 1) & 1) * 64;

    const float* xp = x + ((size_t)(b * CC + cbase)) * NN + n;
    float xr[64];
#pragma unroll
    for (int c = 0; c < 64; ++c) xr[c] = xp[(size_t)c * NN];

    const float* wp = w + obase * 64;
    float buf[16];
#pragma unroll
    for (int oi = 0; oi < 16; ++oi) {
        float acc = 0.f;
#pragma unroll
        for (int c = 0; c < 64; ++c) acc = fmaf(wp[oi * 64 + c], xr[c], acc);
        buf[oi] = acc;
    }

    float* yp = Y + (size_t)gnode * CO + obase;   // 64B-aligned (obase%16==0)
#pragma unroll
    for (int q = 0; q < 4; ++q) {
        float4 v = make_float4(buf[4*q], buf[4*q+1], buf[4*q+2], buf[4*q+3]);
        *(float4*)(yp + 4 * q) = v;
    }
}

// ---------------------------------------------------------------------------
// Kernel 2: gather Y rows per edge, relu, mean over K, transpose via LDS
// 1024 blocks x 256 threads; 16 nodes per block (4 waves x 4 nodes).
// ---------------------------------------------------------------------------
#define NPB 16
__global__ __launch_bounds__(256) void edge_gather(
    const int*   __restrict__ ei,    // [2,B,N,K] int32
    const float* __restrict__ Y,     // [B,N,128]
    const float* __restrict__ bias,  // [128]
    float* __restrict__ out)         // [B,128,N]
{
    __shared__ float tile[NPB][129]; // +1 pad: conflict-free both phases

    const int lane = threadIdx.x & 63;
    const int wv   = threadIdx.x >> 6;   // 0..3

    // same chunked XCD swizzle: 1024 blocks -> 128 consecutive work per XCD,
    // so each XCD gathers from a single half-batch of Y (2MB, fits 4MB L2)
    const int bid  = blockIdx.x;
    const int work = (bid & 7) * ((int)gridDim.x >> 3) + (bid >> 3);

    const int node0 = work * NPB;        // global node base (b*N + n0)
    const int b     = node0 >> 12;
    const float* Yb = Y + (size_t)b * NN * CO;

    const float blo = bias[lane];
    const float bhi = bias[lane + 64];

    const int* i0p = ei;                          // edge_index[0] (j)
    const int* i1p = ei + (size_t)BB * NN * KK;   // edge_index[1] (i)

    for (int t = wv; t < NPB; t += 4) {
        const int gnode = node0 + t;
        const size_t ib = (size_t)gnode * KK;
        const int v0 = i0p[ib + (lane & 15)];   // j indices, k = lane&15
        const int v1 = i1p[ib + (lane & 15)];   // i1 indices

        float acc0 = 0.f, acc1 = 0.f;
#pragma unroll
        for (int k = 0; k < KK; ++k) {
            const int i1 = __shfl(v1, k);
            const int j  = __shfl(v0, k);
            const float* Yi = Yb + (size_t)i1 * CO;
            const float* Yj = Yb + (size_t)j  * CO;
            const float a  = Yi[lane];        // o = lane      (x_i part)
            const float c1 = Yi[lane + 64];   // o = lane+64   (x_i part)
            const float c2 = Yj[lane + 64];   // o = lane+64   (x_j part)
            acc0 += fmaxf(a + blo, 0.f);
            acc1 += fmaxf(c2 - c1 + bhi, 0.f);
        }
        tile[t][lane]      = acc0 * (1.f / KK);
        tile[t][lane + 64] = acc1 * (1.f / KK);
    }
    __syncthreads();

    // write-out: lanes span n (coalesced 64B); o covered by wv/lane-hi/r
    const int n0   = node0 & (NN - 1);
    const int nloc = lane & 15;
    const int ob   = wv * 32 + (lane >> 4) * 8;
#pragma unroll
    for (int r = 0; r < 8; ++r) {
        const int o = ob + r;
        out[((size_t)(b * CO + o)) * NN + n0 + nloc] = tile[nloc][o];
    }
}

// ---------------------------------------------------------------------------
// Fallback (only if workspace < 8MB): direct per-(b,n) compute. Slow but safe.
// ---------------------------------------------------------------------------
__global__ __launch_bounds__(128) void edgeconv_fallback(
    const int*   __restrict__ ei,
    const float* __restrict__ x,
    const float* __restrict__ w,
    const float* __restrict__ bias,
    float* __restrict__ out)
{
    const int bn = blockIdx.x;           // b*N + n
    const int b  = bn >> 12;
    const int n  = bn & (NN - 1);
    const int o  = threadIdx.x;
    const int g  = o >> 5;
    const int cbase = (g & 1) * 64;
    const bool useJ = (g >= 2);

    const float* xb = x + (size_t)b * CC * NN;
    const int* i0p = ei;
    const int* i1p = ei + (size_t)BB * NN * KK;

    float wr[64];
#pragma unroll
    for (int c = 0; c < 64; ++c) wr[c] = w[o * 64 + c];

    float acc = 0.f;
    for (int k = 0; k < KK; ++k) {
        const int i1 = i1p[(size_t)bn * KK + k];
        const int j  = i0p[(size_t)bn * KK + k];
        float dot = 0.f;
#pragma unroll
        for (int c = 0; c < 64; ++c) {
            const float xi = xb[(size_t)(cbase + c) * NN + i1];
            const float f  = useJ ? (xb[(size_t)(cbase + c) * NN + j] - xi) : xi;
            dot = fmaf(wr[c], f, dot);
        }
        acc += fmaxf(dot + bias[o], 0.f);
    }
    out[((size_t)(b * CO + o)) * NN + n] = acc * (1.f / KK);
}

extern "C" void kernel_launch(void* const* d_in, const int* in_sizes, int n_in,
                              void* d_out, int out_size, void* d_ws, size_t ws_size,
                              hipStream_t stream) {
    const float* x    = (const float*)d_in[0];
    const int*   ei   = (const int*)d_in[1];
    const float* w    = (const float*)d_in[2];
    const float* bias = (const float*)d_in[3];
    float* out = (float*)d_out;

    const size_t need = (size_t)BB * NN * CO * sizeof(float); // 8 MB for Y
    if (ws_size >= need) {
        float* Y = (float*)d_ws;
        precompute_y<<<dim3(BB * NN / 64), dim3(512), 0, stream>>>(x, w, Y);
        edge_gather<<<dim3(BB * NN / NPB), dim3(256), 0, stream>>>(ei, Y, bias, out);
    } else {
        edgeconv_fallback<<<dim3(BB * NN), dim3(128), 0, stream>>>(ei, x, w, bias, out);
    }
}